// Round 18
// baseline (245.616 us; speedup 1.0000x reference)
//
#include <hip/hip_runtime.h>

// CentroidPool: argmin_k ||x_i - c_k||^2, N=131072, K=1024, D=128, fp32.
// = argmin_k (0.5||c_k||^2 - x.c_k).
// r8-r16 lesson: 3-term bf16 MFMA pass A pinned at ~105us (2x its 49.7us
// MFMA floor) across every shape/occupancy/schedule. This round attacks
// the WORK: fp16 1-term approx (hi(x).hi(c), one MFMA per tile-step,
// floor 16.6us) with a SOUND per-row error bound:
//   |x.c - hx.hc| <= 2*2^-11*||x||*||c||, ||c|| <= sqrt(128) (c in [0,1)),
//   + fp32-accum 0.005 + mantissa-pack 2^-12*(64+11.32||x||) + slop
//   => eps_row = 0.0276*||x|| + 0.042   (||x|| exact, from fragment load)
// Rows with approx-gap <= eps_row go to pass B (exact fp32). More rows
// flagged than bf16-3term, but pass B is parallel & cheap; correctness
// degrades gracefully into pass B, never into wrong output.
// Pass A is 1 wave/block, wave-private LDS, ZERO barriers, counted vmcnt.
// (r17 was a compile failure: __float2half w/o hip_fp16.h; now using
// native _Float16 casts + bit-cast union, no header needed.)

constexpr int N = 131072;
constexpr int K = 1024;
constexpr int D = 128;

typedef __attribute__((ext_vector_type(8))) _Float16 half8;
typedef __attribute__((ext_vector_type(4))) float f32x4;

typedef const __attribute__((address_space(1))) uint* gas_uint;
typedef __attribute__((address_space(3))) uint* las_uint;

union UH { uint4 u; half8 h; };
__device__ inline half8 as_h8(uint4 v) { UH x; x.u = v; return x.h; }

union H2U { _Float16 h[2]; uint u; };
__device__ inline uint fp16pk(float a, float b) {
    H2U x;
    x.h[0] = (_Float16)a; // v_cvt_f16_f32, RNE
    x.h[1] = (_Float16)b;
    return x.u;
}

// ---- prep: counter zero + 0.5*||c_k||^2 (fp32 exact) + fp16 coords,
// pre-swizzled per-tile layout. Tile kt (32 k) = 8192 B; row m (k=kt*32+m),
// 16B-group g (d = 8g..8g+7): offset m*256 + ((g^(m&15))<<4).
__global__ __launch_bounds__(256) void prep_kernel(
    const float* __restrict__ coords, float* __restrict__ c2half,
    uint* __restrict__ chi, int* __restrict__ counter) {
    if (blockIdx.x == 0 && threadIdx.x == 0) counter[0] = 0;
    const int k = blockIdx.x * 4 + (threadIdx.x >> 6); // one k-row per wave
    const int dw = threadIdx.x & 63;                   // 2 d per thread
    float a = coords[k * D + 2 * dw], b = coords[k * D + 2 * dw + 1];
    const int g = dw >> 2, sub = dw & 3, kt = k >> 5, m = k & 31;
    char* base = (char*)chi + (size_t)kt * 8192 + m * 256 +
                 ((g ^ (m & 15)) << 4) + sub * 4;
    *(uint*)base = fp16pk(a, b);
    float s = fmaf(a, a, b * b);
#pragma unroll
    for (int off = 1; off < 64; off <<= 1) s += __shfl_xor(s, off);
    if (dw == 0) c2half[k] = 0.5f * s;
}

// ---- precompute: coordsT[d][k] = coords[k][d] (LDS-tiled, coalesced) ----
__global__ __launch_bounds__(256) void transpose_kernel(
    const float* __restrict__ coords, float* __restrict__ coordsT) {
    __shared__ float tile[64][65];
    const int k0 = blockIdx.x * 64;
    const int d0 = blockIdx.y * 64;
    const int tx = threadIdx.x & 63, ty = threadIdx.x >> 6;
#pragma unroll
    for (int i = 0; i < 64; i += 4)
        tile[ty + i][tx] = coords[(size_t)(k0 + ty + i) * D + d0 + tx];
    __syncthreads();
#pragma unroll
    for (int i = 0; i < 64; i += 4)
        coordsT[(size_t)(d0 + ty + i) * K + k0 + tx] = tile[tx][ty + i];
}

// ---- pass A: fp16 1-term 16x16x32 MFMA, 1 wave/block, 64 rows/wave,
// wave-private LDS double-buffer, NO barriers, counted vmcnt ----
__global__ __launch_bounds__(64, 2) void centroid_mfma_kernel(
    const float* __restrict__ latent, const uint* __restrict__ chi,
    const float* __restrict__ c2, int* __restrict__ out,
    int* __restrict__ counter, int* __restrict__ list) {
    __shared__ __align__(16) char smem[20480]; // 2 x 8K dbuf + 4K c2
    const int l = threadIdx.x;
    const int l15 = l & 15, l4 = l >> 4; // l4 in 0..3
    const int rowbase = blockIdx.x * 64;

    // B-frags (latent, negated, fp16) + exact row norms.
    // lane holds row rowbase+grp*16+l15, d in {l4*8 + 32s .. +8}.
    uint4 bh[4][4];
    float n2[4];
#pragma unroll
    for (int grp = 0; grp < 4; ++grp) {
        const float* rp =
            latent + (size_t)(rowbase + grp * 16 + l15) * D + l4 * 8;
        float s2 = 0.f;
#pragma unroll
        for (int s = 0; s < 4; ++s) {
            float4 u = *(const float4*)(rp + 32 * s);
            float4 v = *(const float4*)(rp + 32 * s + 4);
            s2 += u.x * u.x + u.y * u.y + u.z * u.z + u.w * u.w +
                  v.x * v.x + v.y * v.y + v.z * v.z + v.w * v.w;
            bh[grp][s] = make_uint4(fp16pk(-u.x, -u.y), fp16pk(-u.z, -u.w),
                                    fp16pk(-v.x, -v.y), fp16pk(-v.z, -v.w));
        }
        n2[grp] = s2;
    }
#pragma unroll
    for (int grp = 0; grp < 4; ++grp) { // full ||x||^2 on all 4 partner lanes
        n2[grp] += __shfl_xor(n2[grp], 16);
        n2[grp] += __shfl_xor(n2[grp], 32);
    }

    // c2 -> wave-private LDS (4 KB at 16384); same-wave RAW is in-order
    {
        float4* dst = (float4*)(smem + 16384);
        const float4* src = (const float4*)c2;
#pragma unroll
        for (int i = 0; i < 4; ++i) dst[i * 64 + l] = src[i * 64 + l];
    }

    // staging: whole 8 KB tile per wave, 8 x 1KB global_load_lds
    const char* gsrc0 = (const char*)chi + (l << 4);
#pragma unroll
    for (int i = 0; i < 8; ++i) // tile 0 -> buf 0
        __builtin_amdgcn_global_load_lds((gas_uint)(gsrc0 + i * 1024),
                                         (las_uint)(smem + i * 1024), 16, 0, 0);
#pragma unroll
    for (int i = 0; i < 8; ++i) // tile 1 -> buf 1
        __builtin_amdgcn_global_load_lds((gas_uint)(gsrc0 + 8192 + i * 1024),
                                         (las_uint)(smem + 8192 + i * 1024),
                                         16, 0, 0);

    // packed-index trackers; k rides in low 10 mantissa bits
    float m1[4] = {3.4e38f, 3.4e38f, 3.4e38f, 3.4e38f};
    float m2[4] = {3.4e38f, 3.4e38f, 3.4e38f, 3.4e38f};
    uint kpack[8]; // k for (ks,r), advanced +32 per tile
#pragma unroll
    for (int ks = 0; ks < 2; ++ks)
#pragma unroll
        for (int r = 0; r < 4; ++r) kpack[ks * 4 + r] = ks * 16 + l4 * 4 + r;
    const float* c2l = (const float*)(smem + 16384);

#pragma unroll 1
    for (int t = 0; t < 32; ++t) {
        const int buf = t & 1;
        // counted wait: tile t's 8 loads retired; t+1's 8 stay in flight
        if (t < 31)
            asm volatile("s_waitcnt vmcnt(8)" ::: "memory");
        else
            asm volatile("s_waitcnt vmcnt(0)" ::: "memory");
        __builtin_amdgcn_sched_barrier(0);

        const int k0 = t * 32;
        f32x4 acc[2][4]; // [ks][grp]: D[k=k0+ks*16+l4*4+r][row=..grp*16+l15]
#pragma unroll
        for (int ks = 0; ks < 2; ++ks) {
            float4 cq = *(const float4*)(c2l + k0 + ks * 16 + l4 * 4);
#pragma unroll
            for (int grp = 0; grp < 4; ++grp) {
                acc[ks][grp][0] = cq.x;
                acc[ks][grp][1] = cq.y;
                acc[ks][grp][2] = cq.z;
                acc[ks][grp][3] = cq.w;
            }
        }

        const char* lhs = smem + buf * 8192;
        __builtin_amdgcn_s_setprio(1);
#pragma unroll
        for (int s = 0; s < 4; ++s) {
            half8 a[2];
#pragma unroll
            for (int ks = 0; ks < 2; ++ks) {
                const int m = ks * 16 + l15;
                const int g = l4 + 4 * s;
                a[ks] = *(const half8*)(lhs + m * 256 + ((g ^ (m & 15)) << 4));
            }
#pragma unroll
            for (int ks = 0; ks < 2; ++ks)
#pragma unroll
                for (int grp = 0; grp < 4; ++grp)
                    acc[ks][grp] = __builtin_amdgcn_mfma_f32_16x16x32_f16(
                        a[ks], as_h8(bh[grp][s]), acc[ks][grp], 0, 0, 0);
        }
        __builtin_amdgcn_s_setprio(0);
        __builtin_amdgcn_sched_barrier(0);

        // insert: pack k into low 10 mantissa bits, then min/med3 only
#pragma unroll
        for (int ks = 0; ks < 2; ++ks) {
#pragma unroll
            for (int r = 0; r < 4; ++r) {
                const uint kk = kpack[ks * 4 + r];
#pragma unroll
                for (int grp = 0; grp < 4; ++grp) {
                    uint pb = (__float_as_uint(acc[ks][grp][r]) & 0xFFFFFC00u) | kk;
                    float vp = __uint_as_float(pb);
                    m2[grp] = __builtin_amdgcn_fmed3f(vp, m1[grp], m2[grp]);
                    m1[grp] = fminf(m1[grp], vp);
                }
            }
        }
#pragma unroll
        for (int i = 0; i < 8; ++i) kpack[i] += 32;

        // all LDS reads of this buf complete before DMA overwrites it
        asm volatile("s_waitcnt lgkmcnt(0)" ::: "memory");
        __builtin_amdgcn_sched_barrier(0);
        if (t < 30) {
            const char* gs = gsrc0 + (size_t)(t + 2) * 8192;
            char* ls = smem + buf * 8192;
#pragma unroll
            for (int i = 0; i < 8; ++i)
                __builtin_amdgcn_global_load_lds((gas_uint)(gs + i * 1024),
                                                 (las_uint)(ls + i * 1024),
                                                 16, 0, 0);
        }
    }

    // merge k-partitions: lanes l, l^16, l^32, l^48 hold same rows (l15)
#pragma unroll
    for (int off = 16; off <= 32; off <<= 1) {
#pragma unroll
        for (int grp = 0; grp < 4; ++grp) {
            float om = __shfl_xor(m1[grp], off);
            float o2 = __shfl_xor(m2[grp], off);
            m2[grp] = fminf(fminf(m2[grp], o2), fmaxf(m1[grp], om));
            m1[grp] = fminf(m1[grp], om);
        }
    }

    // lanes 0..15 own rows rowbase + grp*16 + l; per-row sound threshold
    bool flg[4];
    unsigned long long bm[4];
    int total = 0;
#pragma unroll
    for (int grp = 0; grp < 4; ++grp) {
        float eps = 0.0276f * sqrtf(n2[grp]) + 0.042f;
        flg[grp] = (l < 16) && ((m2[grp] - m1[grp]) <= eps);
        bm[grp] = __ballot(flg[grp]);
        total += __popcll(bm[grp]);
    }
    int pos = 0;
    if (l == 0 && total) pos = atomicAdd(counter, total);
    pos = __shfl(pos, 0);
    if (l < 16) {
        int run = pos;
#pragma unroll
        for (int grp = 0; grp < 4; ++grp) {
            out[rowbase + grp * 16 + l] = (int)(__float_as_uint(m1[grp]) & 1023u);
            if (flg[grp])
                list[run + __popcll(bm[grp] & ((1ull << l) - 1ull))] =
                    rowbase + grp * 16 + l;
            run += __popcll(bm[grp]);
        }
    }
}

// ---- pass B: exact fp32 recompute, 4 rows/wave-task, coalesced coordsT ----
__global__ __launch_bounds__(256) void centroid_exact_kernel(
    const float* __restrict__ latent, const float* __restrict__ coordsT,
    const float* __restrict__ c2, const int* __restrict__ cnt_list,
    int* __restrict__ out) {
    const int count = cnt_list[0];
    const int* list = cnt_list + 16;
    const int lane = threadIdx.x & 63;
    const int gw = (blockIdx.x * 256 + threadIdx.x) >> 6;
    const int nwaves = gridDim.x * 4;
    // lane owns k = c*64 + lane, c = 0..15 (coalesced coordsT reads)

    for (int task = gw; task * 4 < count; task += nwaves) {
        const int base = task * 4;
        const int nr = min(4, count - base);
        const float* xp[4];
        int rows[4];
#pragma unroll
        for (int j = 0; j < 4; ++j) {
            int idx = base + (j < nr ? j : nr - 1);
            rows[j] = __builtin_amdgcn_readfirstlane(list[idx]);
            xp[j] = latent + (size_t)rows[j] * D;
        }

        float acc[16][4];
#pragma unroll
        for (int c = 0; c < 16; ++c) {
            float cc = c2[c * 64 + lane];
#pragma unroll
            for (int j = 0; j < 4; ++j) acc[c][j] = cc;
        }

#pragma unroll 1
        for (int d4 = 0; d4 < D / 4; ++d4) {
            float4 xq[4];
#pragma unroll
            for (int j = 0; j < 4; ++j)
                xq[j] = *(const float4*)(xp[j] + 4 * d4);
            float ct[4][16];
#pragma unroll
            for (int dd = 0; dd < 4; ++dd)
#pragma unroll
                for (int c = 0; c < 16; ++c)
                    ct[dd][c] = coordsT[(size_t)(4 * d4 + dd) * K + c * 64 + lane];
#pragma unroll
            for (int dd = 0; dd < 4; ++dd) {
#pragma unroll
                for (int c = 0; c < 16; ++c) {
#pragma unroll
                    for (int j = 0; j < 4; ++j) {
                        float xv = (dd == 0) ? xq[j].x
                                 : (dd == 1) ? xq[j].y
                                 : (dd == 2) ? xq[j].z : xq[j].w;
                        acc[c][j] = fmaf(-xv, ct[dd][c], acc[c][j]);
                    }
                }
            }
        }

#pragma unroll
        for (int j = 0; j < 4; ++j) {
            float m1 = acc[0][j];
            int i1 = lane;
#pragma unroll
            for (int c = 1; c < 16; ++c) {
                const int kk = c * 64 + lane;
                if (acc[c][j] < m1) { m1 = acc[c][j]; i1 = kk; }
            }
#pragma unroll
            for (int off = 1; off < 64; off <<= 1) {
                float om = __shfl_xor(m1, off);
                int oi = __shfl_xor(i1, off);
                if (om < m1 || (om == m1 && oi < i1)) { m1 = om; i1 = oi; }
            }
            if (lane == 0 && j < nr) out[rows[j]] = i1;
        }
    }
}

extern "C" void kernel_launch(void* const* d_in, const int* in_sizes, int n_in,
                              void* d_out, int out_size, void* d_ws, size_t ws_size,
                              hipStream_t stream) {
    const float* latent = (const float*)d_in[0];
    const float* coords = (const float*)d_in[1];
    int* out = (int*)d_out;

    char* ws = (char*)d_ws;
    size_t off = 0;
    float* c2 = (float*)(ws + off); off += 4096;
    uint* chi = (uint*)(ws + off); off += 262144;   // fp16 pre-swizzled
    float* coordsT = (float*)(ws + off); off += 524288;
    int* cnt_list = (int*)(ws + off); off += 64 + 524288;
    int* counter = cnt_list;
    int* list = cnt_list + 16;

    prep_kernel<<<K / 4, 256, 0, stream>>>(coords, c2, chi, counter);
    {
        dim3 g(K / 64, D / 64);
        transpose_kernel<<<g, 256, 0, stream>>>(coords, coordsT);
    }
    // 1 wave/block, 64 rows, full K: 2048 blocks = 8 waves/CU, no barriers
    centroid_mfma_kernel<<<N / 64, 64, 0, stream>>>(latent, chi, c2, out,
                                                    counter, list);
    centroid_exact_kernel<<<2048, 256, 0, stream>>>(latent, coordsT, c2,
                                                    cnt_list, out);
}

// Round 19
// 131.392 us; speedup vs baseline: 1.8693x; 1.8693x over previous
//
#include <hip/hip_runtime.h>

// CentroidPool: argmin_k ||x_i - c_k||^2, N=131072, K=1024, D=128, fp32.
// = argmin_k (0.5||c_k||^2 - x.c_k).
// r18 result: 1-wave no-barrier pass A works (~28us @ 1 MFMA/frag) but the
// 1-term fp16 bound (eps~0.35) flagged 36% of rows -> pass B 204us.
// r19: 2-TERM fp16 split of the LATENT side (registers only -- no extra
// LDS/staging): (hx+lx).hc with hx,lx = fp16 hi/residual of -x.
// fp16 x fp16 products are EXACT in fp32 (11+11 <= 24 bits), so error =
//   x.lc (coords rounding)   <= 2^-12*sqrt(128)*||x|| = 0.00277*||x||
// + latent double-round      <= 2^-23*||x||_1 (negligible)
// + fp32 accum ~1.1e-3 + mantissa-pack ~8e-3
// => eps_row = 0.0028*||x|| + 0.015  (~0.047: r8's proven flag regime)
// Pass A: 1 wave/block, wave-private LDS dbuf, ZERO barriers, counted
// vmcnt, 16 MFMA/tile. Pass B: exact fp32 recompute (coalesced coordsT).

constexpr int N = 131072;
constexpr int K = 1024;
constexpr int D = 128;

typedef __attribute__((ext_vector_type(8))) _Float16 half8;
typedef __attribute__((ext_vector_type(4))) float f32x4;

typedef const __attribute__((address_space(1))) uint* gas_uint;
typedef __attribute__((address_space(3))) uint* las_uint;

union UH { uint4 u; half8 h; };
__device__ inline half8 as_h8(uint4 v) { UH x; x.u = v; return x.h; }

union H2U { _Float16 h[2]; uint u; };
__device__ inline uint fp16pk(float a, float b) {
    H2U x;
    x.h[0] = (_Float16)a; // v_cvt_f16_f32, RNE
    x.h[1] = (_Float16)b;
    return x.u;
}
// hi = fp16(a), lo = fp16(a - (float)hi); returns packed pair per value
__device__ inline void fp16split(float a, _Float16& hi, _Float16& lo) {
    hi = (_Float16)a;
    lo = (_Float16)(a - (float)hi);
}
__device__ inline void pk2(float a, float b, uint& h, uint& l) {
    _Float16 ha, la, hb, lb;
    fp16split(a, ha, la);
    fp16split(b, hb, lb);
    H2U x, y;
    x.h[0] = ha; x.h[1] = hb;
    y.h[0] = la; y.h[1] = lb;
    h = x.u;
    l = y.u;
}

// ---- prep: counter zero + 0.5*||c_k||^2 (fp32 exact) + fp16 coords,
// pre-swizzled per-tile layout. Tile kt (32 k) = 8192 B; row m (k=kt*32+m),
// 16B-group g (d = 8g..8g+7): offset m*256 + ((g^(m&15))<<4).
__global__ __launch_bounds__(256) void prep_kernel(
    const float* __restrict__ coords, float* __restrict__ c2half,
    uint* __restrict__ chi, int* __restrict__ counter) {
    if (blockIdx.x == 0 && threadIdx.x == 0) counter[0] = 0;
    const int k = blockIdx.x * 4 + (threadIdx.x >> 6); // one k-row per wave
    const int dw = threadIdx.x & 63;                   // 2 d per thread
    float a = coords[k * D + 2 * dw], b = coords[k * D + 2 * dw + 1];
    const int g = dw >> 2, sub = dw & 3, kt = k >> 5, m = k & 31;
    char* base = (char*)chi + (size_t)kt * 8192 + m * 256 +
                 ((g ^ (m & 15)) << 4) + sub * 4;
    *(uint*)base = fp16pk(a, b);
    float s = fmaf(a, a, b * b);
#pragma unroll
    for (int off = 1; off < 64; off <<= 1) s += __shfl_xor(s, off);
    if (dw == 0) c2half[k] = 0.5f * s;
}

// ---- precompute: coordsT[d][k] = coords[k][d] (LDS-tiled, coalesced) ----
__global__ __launch_bounds__(256) void transpose_kernel(
    const float* __restrict__ coords, float* __restrict__ coordsT) {
    __shared__ float tile[64][65];
    const int k0 = blockIdx.x * 64;
    const int d0 = blockIdx.y * 64;
    const int tx = threadIdx.x & 63, ty = threadIdx.x >> 6;
#pragma unroll
    for (int i = 0; i < 64; i += 4)
        tile[ty + i][tx] = coords[(size_t)(k0 + ty + i) * D + d0 + tx];
    __syncthreads();
#pragma unroll
    for (int i = 0; i < 64; i += 4)
        coordsT[(size_t)(d0 + ty + i) * K + k0 + tx] = tile[tx][ty + i];
}

// ---- pass A: fp16 2-term (latent hi+lo) 16x16x32 MFMA, 1 wave/block,
// 64 rows/wave, wave-private LDS double-buffer, NO barriers ----
__global__ __launch_bounds__(64, 2) void centroid_mfma_kernel(
    const float* __restrict__ latent, const uint* __restrict__ chi,
    const float* __restrict__ c2, int* __restrict__ out,
    int* __restrict__ counter, int* __restrict__ list) {
    __shared__ __align__(16) char smem[20480]; // 2 x 8K dbuf + 4K c2
    const int l = threadIdx.x;
    const int l15 = l & 15, l4 = l >> 4; // l4 in 0..3
    const int rowbase = blockIdx.x * 64;

    // B-frags (latent, negated, fp16 hi + residual lo) + exact row norms.
    // lane holds row rowbase+grp*16+l15, d in {l4*8 + 32s .. +8}.
    uint4 bh[4][4], bl[4][4];
    float n2[4];
#pragma unroll
    for (int grp = 0; grp < 4; ++grp) {
        const float* rp =
            latent + (size_t)(rowbase + grp * 16 + l15) * D + l4 * 8;
        float s2 = 0.f;
#pragma unroll
        for (int s = 0; s < 4; ++s) {
            float4 u = *(const float4*)(rp + 32 * s);
            float4 v = *(const float4*)(rp + 32 * s + 4);
            s2 += u.x * u.x + u.y * u.y + u.z * u.z + u.w * u.w +
                  v.x * v.x + v.y * v.y + v.z * v.z + v.w * v.w;
            uint h0, o0, h1, o1, h2, o2, h3, o3;
            pk2(-u.x, -u.y, h0, o0);
            pk2(-u.z, -u.w, h1, o1);
            pk2(-v.x, -v.y, h2, o2);
            pk2(-v.z, -v.w, h3, o3);
            bh[grp][s] = make_uint4(h0, h1, h2, h3);
            bl[grp][s] = make_uint4(o0, o1, o2, o3);
        }
        n2[grp] = s2;
    }
#pragma unroll
    for (int grp = 0; grp < 4; ++grp) { // full ||x||^2 on all 4 partner lanes
        n2[grp] += __shfl_xor(n2[grp], 16);
        n2[grp] += __shfl_xor(n2[grp], 32);
    }

    // c2 -> wave-private LDS (4 KB at 16384); same-wave RAW is in-order
    {
        float4* dst = (float4*)(smem + 16384);
        const float4* src = (const float4*)c2;
#pragma unroll
        for (int i = 0; i < 4; ++i) dst[i * 64 + l] = src[i * 64 + l];
    }

    // staging: whole 8 KB tile per wave, 8 x 1KB global_load_lds
    const char* gsrc0 = (const char*)chi + (l << 4);
#pragma unroll
    for (int i = 0; i < 8; ++i) // tile 0 -> buf 0
        __builtin_amdgcn_global_load_lds((gas_uint)(gsrc0 + i * 1024),
                                         (las_uint)(smem + i * 1024), 16, 0, 0);
#pragma unroll
    for (int i = 0; i < 8; ++i) // tile 1 -> buf 1
        __builtin_amdgcn_global_load_lds((gas_uint)(gsrc0 + 8192 + i * 1024),
                                         (las_uint)(smem + 8192 + i * 1024),
                                         16, 0, 0);

    // packed-index trackers; k rides in low 10 mantissa bits
    float m1[4] = {3.4e38f, 3.4e38f, 3.4e38f, 3.4e38f};
    float m2[4] = {3.4e38f, 3.4e38f, 3.4e38f, 3.4e38f};
    uint kpack[8]; // k for (ks,r), advanced +32 per tile
#pragma unroll
    for (int ks = 0; ks < 2; ++ks)
#pragma unroll
        for (int r = 0; r < 4; ++r) kpack[ks * 4 + r] = ks * 16 + l4 * 4 + r;
    const float* c2l = (const float*)(smem + 16384);

#pragma unroll 1
    for (int t = 0; t < 32; ++t) {
        const int buf = t & 1;
        // counted wait: tile t's 8 loads retired; t+1's 8 stay in flight
        if (t < 31)
            asm volatile("s_waitcnt vmcnt(8)" ::: "memory");
        else
            asm volatile("s_waitcnt vmcnt(0)" ::: "memory");
        __builtin_amdgcn_sched_barrier(0);

        const int k0 = t * 32;
        f32x4 acc[2][4]; // [ks][grp]: D[k=k0+ks*16+l4*4+r][row=..grp*16+l15]
#pragma unroll
        for (int ks = 0; ks < 2; ++ks) {
            float4 cq = *(const float4*)(c2l + k0 + ks * 16 + l4 * 4);
#pragma unroll
            for (int grp = 0; grp < 4; ++grp) {
                acc[ks][grp][0] = cq.x;
                acc[ks][grp][1] = cq.y;
                acc[ks][grp][2] = cq.z;
                acc[ks][grp][3] = cq.w;
            }
        }

        const char* lhs = smem + buf * 8192;
        __builtin_amdgcn_s_setprio(1);
#pragma unroll
        for (int s = 0; s < 4; ++s) {
            half8 a[2];
#pragma unroll
            for (int ks = 0; ks < 2; ++ks) {
                const int m = ks * 16 + l15;
                const int g = l4 + 4 * s;
                a[ks] = *(const half8*)(lhs + m * 256 + ((g ^ (m & 15)) << 4));
            }
#pragma unroll
            for (int ks = 0; ks < 2; ++ks)
#pragma unroll
                for (int grp = 0; grp < 4; ++grp) {
                    acc[ks][grp] = __builtin_amdgcn_mfma_f32_16x16x32_f16(
                        a[ks], as_h8(bh[grp][s]), acc[ks][grp], 0, 0, 0);
                    acc[ks][grp] = __builtin_amdgcn_mfma_f32_16x16x32_f16(
                        a[ks], as_h8(bl[grp][s]), acc[ks][grp], 0, 0, 0);
                }
        }
        __builtin_amdgcn_s_setprio(0);
        __builtin_amdgcn_sched_barrier(0);

        // insert: pack k into low 10 mantissa bits, then min/med3 only
#pragma unroll
        for (int ks = 0; ks < 2; ++ks) {
#pragma unroll
            for (int r = 0; r < 4; ++r) {
                const uint kk = kpack[ks * 4 + r];
#pragma unroll
                for (int grp = 0; grp < 4; ++grp) {
                    uint pb = (__float_as_uint(acc[ks][grp][r]) & 0xFFFFFC00u) | kk;
                    float vp = __uint_as_float(pb);
                    m2[grp] = __builtin_amdgcn_fmed3f(vp, m1[grp], m2[grp]);
                    m1[grp] = fminf(m1[grp], vp);
                }
            }
        }
#pragma unroll
        for (int i = 0; i < 8; ++i) kpack[i] += 32;

        // all LDS reads of this buf complete before DMA overwrites it
        asm volatile("s_waitcnt lgkmcnt(0)" ::: "memory");
        __builtin_amdgcn_sched_barrier(0);
        if (t < 30) {
            const char* gs = gsrc0 + (size_t)(t + 2) * 8192;
            char* ls = smem + buf * 8192;
#pragma unroll
            for (int i = 0; i < 8; ++i)
                __builtin_amdgcn_global_load_lds((gas_uint)(gs + i * 1024),
                                                 (las_uint)(ls + i * 1024),
                                                 16, 0, 0);
        }
    }

    // merge k-partitions: lanes l, l^16, l^32, l^48 hold same rows (l15)
#pragma unroll
    for (int off = 16; off <= 32; off <<= 1) {
#pragma unroll
        for (int grp = 0; grp < 4; ++grp) {
            float om = __shfl_xor(m1[grp], off);
            float o2 = __shfl_xor(m2[grp], off);
            m2[grp] = fminf(fminf(m2[grp], o2), fmaxf(m1[grp], om));
            m1[grp] = fminf(m1[grp], om);
        }
    }

    // lanes 0..15 own rows rowbase + grp*16 + l; per-row sound threshold
    bool flg[4];
    unsigned long long bm[4];
    int total = 0;
#pragma unroll
    for (int grp = 0; grp < 4; ++grp) {
        float eps = 0.0028f * sqrtf(n2[grp]) + 0.015f;
        flg[grp] = (l < 16) && ((m2[grp] - m1[grp]) <= eps);
        bm[grp] = __ballot(flg[grp]);
        total += __popcll(bm[grp]);
    }
    int pos = 0;
    if (l == 0 && total) pos = atomicAdd(counter, total);
    pos = __shfl(pos, 0);
    if (l < 16) {
        int run = pos;
#pragma unroll
        for (int grp = 0; grp < 4; ++grp) {
            out[rowbase + grp * 16 + l] = (int)(__float_as_uint(m1[grp]) & 1023u);
            if (flg[grp])
                list[run + __popcll(bm[grp] & ((1ull << l) - 1ull))] =
                    rowbase + grp * 16 + l;
            run += __popcll(bm[grp]);
        }
    }
}

// ---- pass B: exact fp32 recompute, 4 rows/wave-task, coalesced coordsT ----
__global__ __launch_bounds__(256) void centroid_exact_kernel(
    const float* __restrict__ latent, const float* __restrict__ coordsT,
    const float* __restrict__ c2, const int* __restrict__ cnt_list,
    int* __restrict__ out) {
    const int count = cnt_list[0];
    const int* list = cnt_list + 16;
    const int lane = threadIdx.x & 63;
    const int gw = (blockIdx.x * 256 + threadIdx.x) >> 6;
    const int nwaves = gridDim.x * 4;
    // lane owns k = c*64 + lane, c = 0..15 (coalesced coordsT reads)

    for (int task = gw; task * 4 < count; task += nwaves) {
        const int base = task * 4;
        const int nr = min(4, count - base);
        const float* xp[4];
        int rows[4];
#pragma unroll
        for (int j = 0; j < 4; ++j) {
            int idx = base + (j < nr ? j : nr - 1);
            rows[j] = __builtin_amdgcn_readfirstlane(list[idx]);
            xp[j] = latent + (size_t)rows[j] * D;
        }

        float acc[16][4];
#pragma unroll
        for (int c = 0; c < 16; ++c) {
            float cc = c2[c * 64 + lane];
#pragma unroll
            for (int j = 0; j < 4; ++j) acc[c][j] = cc;
        }

#pragma unroll 1
        for (int d4 = 0; d4 < D / 4; ++d4) {
            float4 xq[4];
#pragma unroll
            for (int j = 0; j < 4; ++j)
                xq[j] = *(const float4*)(xp[j] + 4 * d4);
            float ct[4][16];
#pragma unroll
            for (int dd = 0; dd < 4; ++dd)
#pragma unroll
                for (int c = 0; c < 16; ++c)
                    ct[dd][c] = coordsT[(size_t)(4 * d4 + dd) * K + c * 64 + lane];
#pragma unroll
            for (int dd = 0; dd < 4; ++dd) {
#pragma unroll
                for (int c = 0; c < 16; ++c) {
#pragma unroll
                    for (int j = 0; j < 4; ++j) {
                        float xv = (dd == 0) ? xq[j].x
                                 : (dd == 1) ? xq[j].y
                                 : (dd == 2) ? xq[j].z : xq[j].w;
                        acc[c][j] = fmaf(-xv, ct[dd][c], acc[c][j]);
                    }
                }
            }
        }

#pragma unroll
        for (int j = 0; j < 4; ++j) {
            float m1 = acc[0][j];
            int i1 = lane;
#pragma unroll
            for (int c = 1; c < 16; ++c) {
                const int kk = c * 64 + lane;
                if (acc[c][j] < m1) { m1 = acc[c][j]; i1 = kk; }
            }
#pragma unroll
            for (int off = 1; off < 64; off <<= 1) {
                float om = __shfl_xor(m1, off);
                int oi = __shfl_xor(i1, off);
                if (om < m1 || (om == m1 && oi < i1)) { m1 = om; i1 = oi; }
            }
            if (lane == 0 && j < nr) out[rows[j]] = i1;
        }
    }
}

extern "C" void kernel_launch(void* const* d_in, const int* in_sizes, int n_in,
                              void* d_out, int out_size, void* d_ws, size_t ws_size,
                              hipStream_t stream) {
    const float* latent = (const float*)d_in[0];
    const float* coords = (const float*)d_in[1];
    int* out = (int*)d_out;

    char* ws = (char*)d_ws;
    size_t off = 0;
    float* c2 = (float*)(ws + off); off += 4096;
    uint* chi = (uint*)(ws + off); off += 262144;   // fp16 pre-swizzled
    float* coordsT = (float*)(ws + off); off += 524288;
    int* cnt_list = (int*)(ws + off); off += 64 + 524288;
    int* counter = cnt_list;
    int* list = cnt_list + 16;

    prep_kernel<<<K / 4, 256, 0, stream>>>(coords, c2, chi, counter);
    {
        dim3 g(K / 64, D / 64);
        transpose_kernel<<<g, 256, 0, stream>>>(coords, coordsT);
    }
    // 1 wave/block, 64 rows, full K: 2048 blocks = 8 waves/CU, no barriers
    centroid_mfma_kernel<<<N / 64, 64, 0, stream>>>(latent, chi, c2, out,
                                                    counter, list);
    centroid_exact_kernel<<<2048, 256, 0, stream>>>(latent, coordsT, c2,
                                                    cnt_list, out);
}

// Round 20
// 131.302 us; speedup vs baseline: 1.8706x; 1.0007x over previous
//
#include <hip/hip_runtime.h>

// CentroidPool: argmin_k ||x_i - c_k||^2, N=131072, K=1024, D=128, fp32.
// = argmin_k (0.5||c_k||^2 - x.c_k).
// r19: 2-term fp16 latent split, sound eps_row = 0.0028*||x||+0.015 ->
// pass B small (r8 regime). But pass A was 88us (vs 35 for 1-term):
// the hi/lo MFMAs were BACK-TO-BACK DEPENDENT on the same accumulator
// (stall ~latency per pair). This also explains the r8-r15 40% MfmaUtil
// plateau (3-term triples on one acc).
// r20: reorder -- per d-slice s, all 8 hi-MFMAs (8 distinct accs) then
// all 8 lo-MFMAs: same-acc dependency distance = 8 issues (~39cy) >=
// MFMA latency. Zero extra registers, pure instruction order.
// Pass A: 1 wave/block, wave-private LDS dbuf, ZERO barriers, counted
// vmcnt. Pass B: exact fp32 recompute (coalesced coordsT).

constexpr int N = 131072;
constexpr int K = 1024;
constexpr int D = 128;

typedef __attribute__((ext_vector_type(8))) _Float16 half8;
typedef __attribute__((ext_vector_type(4))) float f32x4;

typedef const __attribute__((address_space(1))) uint* gas_uint;
typedef __attribute__((address_space(3))) uint* las_uint;

union UH { uint4 u; half8 h; };
__device__ inline half8 as_h8(uint4 v) { UH x; x.u = v; return x.h; }

union H2U { _Float16 h[2]; uint u; };
__device__ inline uint fp16pk(float a, float b) {
    H2U x;
    x.h[0] = (_Float16)a; // v_cvt_f16_f32, RNE
    x.h[1] = (_Float16)b;
    return x.u;
}
// hi = fp16(a), lo = fp16(a - (float)hi)
__device__ inline void fp16split(float a, _Float16& hi, _Float16& lo) {
    hi = (_Float16)a;
    lo = (_Float16)(a - (float)hi);
}
__device__ inline void pk2(float a, float b, uint& h, uint& l) {
    _Float16 ha, la, hb, lb;
    fp16split(a, ha, la);
    fp16split(b, hb, lb);
    H2U x, y;
    x.h[0] = ha; x.h[1] = hb;
    y.h[0] = la; y.h[1] = lb;
    h = x.u;
    l = y.u;
}

// ---- prep: counter zero + 0.5*||c_k||^2 (fp32 exact) + fp16 coords,
// pre-swizzled per-tile layout. Tile kt (32 k) = 8192 B; row m (k=kt*32+m),
// 16B-group g (d = 8g..8g+7): offset m*256 + ((g^(m&15))<<4).
__global__ __launch_bounds__(256) void prep_kernel(
    const float* __restrict__ coords, float* __restrict__ c2half,
    uint* __restrict__ chi, int* __restrict__ counter) {
    if (blockIdx.x == 0 && threadIdx.x == 0) counter[0] = 0;
    const int k = blockIdx.x * 4 + (threadIdx.x >> 6); // one k-row per wave
    const int dw = threadIdx.x & 63;                   // 2 d per thread
    float a = coords[k * D + 2 * dw], b = coords[k * D + 2 * dw + 1];
    const int g = dw >> 2, sub = dw & 3, kt = k >> 5, m = k & 31;
    char* base = (char*)chi + (size_t)kt * 8192 + m * 256 +
                 ((g ^ (m & 15)) << 4) + sub * 4;
    *(uint*)base = fp16pk(a, b);
    float s = fmaf(a, a, b * b);
#pragma unroll
    for (int off = 1; off < 64; off <<= 1) s += __shfl_xor(s, off);
    if (dw == 0) c2half[k] = 0.5f * s;
}

// ---- precompute: coordsT[d][k] = coords[k][d] (LDS-tiled, coalesced) ----
__global__ __launch_bounds__(256) void transpose_kernel(
    const float* __restrict__ coords, float* __restrict__ coordsT) {
    __shared__ float tile[64][65];
    const int k0 = blockIdx.x * 64;
    const int d0 = blockIdx.y * 64;
    const int tx = threadIdx.x & 63, ty = threadIdx.x >> 6;
#pragma unroll
    for (int i = 0; i < 64; i += 4)
        tile[ty + i][tx] = coords[(size_t)(k0 + ty + i) * D + d0 + tx];
    __syncthreads();
#pragma unroll
    for (int i = 0; i < 64; i += 4)
        coordsT[(size_t)(d0 + ty + i) * K + k0 + tx] = tile[tx][ty + i];
}

// ---- pass A: fp16 2-term (latent hi+lo) 16x16x32 MFMA, 1 wave/block,
// 64 rows/wave, wave-private LDS double-buffer, NO barriers ----
__global__ __launch_bounds__(64, 2) void centroid_mfma_kernel(
    const float* __restrict__ latent, const uint* __restrict__ chi,
    const float* __restrict__ c2, int* __restrict__ out,
    int* __restrict__ counter, int* __restrict__ list) {
    __shared__ __align__(16) char smem[20480]; // 2 x 8K dbuf + 4K c2
    const int l = threadIdx.x;
    const int l15 = l & 15, l4 = l >> 4; // l4 in 0..3
    const int rowbase = blockIdx.x * 64;

    // B-frags (latent, negated, fp16 hi + residual lo) + exact row norms.
    uint4 bh[4][4], bl[4][4];
    float n2[4];
#pragma unroll
    for (int grp = 0; grp < 4; ++grp) {
        const float* rp =
            latent + (size_t)(rowbase + grp * 16 + l15) * D + l4 * 8;
        float s2 = 0.f;
#pragma unroll
        for (int s = 0; s < 4; ++s) {
            float4 u = *(const float4*)(rp + 32 * s);
            float4 v = *(const float4*)(rp + 32 * s + 4);
            s2 += u.x * u.x + u.y * u.y + u.z * u.z + u.w * u.w +
                  v.x * v.x + v.y * v.y + v.z * v.z + v.w * v.w;
            uint h0, o0, h1, o1, h2, o2, h3, o3;
            pk2(-u.x, -u.y, h0, o0);
            pk2(-u.z, -u.w, h1, o1);
            pk2(-v.x, -v.y, h2, o2);
            pk2(-v.z, -v.w, h3, o3);
            bh[grp][s] = make_uint4(h0, h1, h2, h3);
            bl[grp][s] = make_uint4(o0, o1, o2, o3);
        }
        n2[grp] = s2;
    }
#pragma unroll
    for (int grp = 0; grp < 4; ++grp) { // full ||x||^2 on all 4 partner lanes
        n2[grp] += __shfl_xor(n2[grp], 16);
        n2[grp] += __shfl_xor(n2[grp], 32);
    }

    // c2 -> wave-private LDS (4 KB at 16384); same-wave RAW is in-order
    {
        float4* dst = (float4*)(smem + 16384);
        const float4* src = (const float4*)c2;
#pragma unroll
        for (int i = 0; i < 4; ++i) dst[i * 64 + l] = src[i * 64 + l];
    }

    // staging: whole 8 KB tile per wave, 8 x 1KB global_load_lds
    const char* gsrc0 = (const char*)chi + (l << 4);
#pragma unroll
    for (int i = 0; i < 8; ++i) // tile 0 -> buf 0
        __builtin_amdgcn_global_load_lds((gas_uint)(gsrc0 + i * 1024),
                                         (las_uint)(smem + i * 1024), 16, 0, 0);
#pragma unroll
    for (int i = 0; i < 8; ++i) // tile 1 -> buf 1
        __builtin_amdgcn_global_load_lds((gas_uint)(gsrc0 + 8192 + i * 1024),
                                         (las_uint)(smem + 8192 + i * 1024),
                                         16, 0, 0);

    // packed-index trackers; k rides in low 10 mantissa bits
    float m1[4] = {3.4e38f, 3.4e38f, 3.4e38f, 3.4e38f};
    float m2[4] = {3.4e38f, 3.4e38f, 3.4e38f, 3.4e38f};
    uint kpack[8]; // k for (ks,r), advanced +32 per tile
#pragma unroll
    for (int ks = 0; ks < 2; ++ks)
#pragma unroll
        for (int r = 0; r < 4; ++r) kpack[ks * 4 + r] = ks * 16 + l4 * 4 + r;
    const float* c2l = (const float*)(smem + 16384);

#pragma unroll 1
    for (int t = 0; t < 32; ++t) {
        const int buf = t & 1;
        // counted wait: tile t's 8 loads retired; t+1's 8 stay in flight
        if (t < 31)
            asm volatile("s_waitcnt vmcnt(8)" ::: "memory");
        else
            asm volatile("s_waitcnt vmcnt(0)" ::: "memory");
        __builtin_amdgcn_sched_barrier(0);

        const int k0 = t * 32;
        f32x4 acc[2][4]; // [ks][grp]: D[k=k0+ks*16+l4*4+r][row=..grp*16+l15]
#pragma unroll
        for (int ks = 0; ks < 2; ++ks) {
            float4 cq = *(const float4*)(c2l + k0 + ks * 16 + l4 * 4);
#pragma unroll
            for (int grp = 0; grp < 4; ++grp) {
                acc[ks][grp][0] = cq.x;
                acc[ks][grp][1] = cq.y;
                acc[ks][grp][2] = cq.z;
                acc[ks][grp][3] = cq.w;
            }
        }

        const char* lhs = smem + buf * 8192;
        __builtin_amdgcn_s_setprio(1);
#pragma unroll
        for (int s = 0; s < 4; ++s) {
            half8 a[2];
#pragma unroll
            for (int ks = 0; ks < 2; ++ks) {
                const int m = ks * 16 + l15;
                const int g = l4 + 4 * s;
                a[ks] = *(const half8*)(lhs + m * 256 + ((g ^ (m & 15)) << 4));
            }
            // all 8 hi-term MFMAs first (8 distinct accs), then all 8
            // lo-term: same-acc dependency distance = 8 issues >= latency
#pragma unroll
            for (int ks = 0; ks < 2; ++ks)
#pragma unroll
                for (int grp = 0; grp < 4; ++grp)
                    acc[ks][grp] = __builtin_amdgcn_mfma_f32_16x16x32_f16(
                        a[ks], as_h8(bh[grp][s]), acc[ks][grp], 0, 0, 0);
#pragma unroll
            for (int ks = 0; ks < 2; ++ks)
#pragma unroll
                for (int grp = 0; grp < 4; ++grp)
                    acc[ks][grp] = __builtin_amdgcn_mfma_f32_16x16x32_f16(
                        a[ks], as_h8(bl[grp][s]), acc[ks][grp], 0, 0, 0);
        }
        __builtin_amdgcn_s_setprio(0);
        __builtin_amdgcn_sched_barrier(0);

        // insert: pack k into low 10 mantissa bits, then min/med3 only
#pragma unroll
        for (int ks = 0; ks < 2; ++ks) {
#pragma unroll
            for (int r = 0; r < 4; ++r) {
                const uint kk = kpack[ks * 4 + r];
#pragma unroll
                for (int grp = 0; grp < 4; ++grp) {
                    uint pb = (__float_as_uint(acc[ks][grp][r]) & 0xFFFFFC00u) | kk;
                    float vp = __uint_as_float(pb);
                    m2[grp] = __builtin_amdgcn_fmed3f(vp, m1[grp], m2[grp]);
                    m1[grp] = fminf(m1[grp], vp);
                }
            }
        }
#pragma unroll
        for (int i = 0; i < 8; ++i) kpack[i] += 32;

        // all LDS reads of this buf complete before DMA overwrites it
        asm volatile("s_waitcnt lgkmcnt(0)" ::: "memory");
        __builtin_amdgcn_sched_barrier(0);
        if (t < 30) {
            const char* gs = gsrc0 + (size_t)(t + 2) * 8192;
            char* ls = smem + buf * 8192;
#pragma unroll
            for (int i = 0; i < 8; ++i)
                __builtin_amdgcn_global_load_lds((gas_uint)(gs + i * 1024),
                                                 (las_uint)(ls + i * 1024),
                                                 16, 0, 0);
        }
    }

    // merge k-partitions: lanes l, l^16, l^32, l^48 hold same rows (l15)
#pragma unroll
    for (int off = 16; off <= 32; off <<= 1) {
#pragma unroll
        for (int grp = 0; grp < 4; ++grp) {
            float om = __shfl_xor(m1[grp], off);
            float o2 = __shfl_xor(m2[grp], off);
            m2[grp] = fminf(fminf(m2[grp], o2), fmaxf(m1[grp], om));
            m1[grp] = fminf(m1[grp], om);
        }
    }

    // lanes 0..15 own rows rowbase + grp*16 + l; per-row sound threshold
    bool flg[4];
    unsigned long long bm[4];
    int total = 0;
#pragma unroll
    for (int grp = 0; grp < 4; ++grp) {
        float eps = 0.0028f * sqrtf(n2[grp]) + 0.015f;
        flg[grp] = (l < 16) && ((m2[grp] - m1[grp]) <= eps);
        bm[grp] = __ballot(flg[grp]);
        total += __popcll(bm[grp]);
    }
    int pos = 0;
    if (l == 0 && total) pos = atomicAdd(counter, total);
    pos = __shfl(pos, 0);
    if (l < 16) {
        int run = pos;
#pragma unroll
        for (int grp = 0; grp < 4; ++grp) {
            out[rowbase + grp * 16 + l] = (int)(__float_as_uint(m1[grp]) & 1023u);
            if (flg[grp])
                list[run + __popcll(bm[grp] & ((1ull << l) - 1ull))] =
                    rowbase + grp * 16 + l;
            run += __popcll(bm[grp]);
        }
    }
}

// ---- pass B: exact fp32 recompute, 4 rows/wave-task, coalesced coordsT ----
__global__ __launch_bounds__(256) void centroid_exact_kernel(
    const float* __restrict__ latent, const float* __restrict__ coordsT,
    const float* __restrict__ c2, const int* __restrict__ cnt_list,
    int* __restrict__ out) {
    const int count = cnt_list[0];
    const int* list = cnt_list + 16;
    const int lane = threadIdx.x & 63;
    const int gw = (blockIdx.x * 256 + threadIdx.x) >> 6;
    const int nwaves = gridDim.x * 4;
    // lane owns k = c*64 + lane, c = 0..15 (coalesced coordsT reads)

    for (int task = gw; task * 4 < count; task += nwaves) {
        const int base = task * 4;
        const int nr = min(4, count - base);
        const float* xp[4];
        int rows[4];
#pragma unroll
        for (int j = 0; j < 4; ++j) {
            int idx = base + (j < nr ? j : nr - 1);
            rows[j] = __builtin_amdgcn_readfirstlane(list[idx]);
            xp[j] = latent + (size_t)rows[j] * D;
        }

        float acc[16][4];
#pragma unroll
        for (int c = 0; c < 16; ++c) {
            float cc = c2[c * 64 + lane];
#pragma unroll
            for (int j = 0; j < 4; ++j) acc[c][j] = cc;
        }

#pragma unroll 1
        for (int d4 = 0; d4 < D / 4; ++d4) {
            float4 xq[4];
#pragma unroll
            for (int j = 0; j < 4; ++j)
                xq[j] = *(const float4*)(xp[j] + 4 * d4);
            float ct[4][16];
#pragma unroll
            for (int dd = 0; dd < 4; ++dd)
#pragma unroll
                for (int c = 0; c < 16; ++c)
                    ct[dd][c] = coordsT[(size_t)(4 * d4 + dd) * K + c * 64 + lane];
#pragma unroll
            for (int dd = 0; dd < 4; ++dd) {
#pragma unroll
                for (int c = 0; c < 16; ++c) {
#pragma unroll
                    for (int j = 0; j < 4; ++j) {
                        float xv = (dd == 0) ? xq[j].x
                                 : (dd == 1) ? xq[j].y
                                 : (dd == 2) ? xq[j].z : xq[j].w;
                        acc[c][j] = fmaf(-xv, ct[dd][c], acc[c][j]);
                    }
                }
            }
        }

#pragma unroll
        for (int j = 0; j < 4; ++j) {
            float m1 = acc[0][j];
            int i1 = lane;
#pragma unroll
            for (int c = 1; c < 16; ++c) {
                const int kk = c * 64 + lane;
                if (acc[c][j] < m1) { m1 = acc[c][j]; i1 = kk; }
            }
#pragma unroll
            for (int off = 1; off < 64; off <<= 1) {
                float om = __shfl_xor(m1, off);
                int oi = __shfl_xor(i1, off);
                if (om < m1 || (om == m1 && oi < i1)) { m1 = om; i1 = oi; }
            }
            if (lane == 0 && j < nr) out[rows[j]] = i1;
        }
    }
}

extern "C" void kernel_launch(void* const* d_in, const int* in_sizes, int n_in,
                              void* d_out, int out_size, void* d_ws, size_t ws_size,
                              hipStream_t stream) {
    const float* latent = (const float*)d_in[0];
    const float* coords = (const float*)d_in[1];
    int* out = (int*)d_out;

    char* ws = (char*)d_ws;
    size_t off = 0;
    float* c2 = (float*)(ws + off); off += 4096;
    uint* chi = (uint*)(ws + off); off += 262144;   // fp16 pre-swizzled
    float* coordsT = (float*)(ws + off); off += 524288;
    int* cnt_list = (int*)(ws + off); off += 64 + 524288;
    int* counter = cnt_list;
    int* list = cnt_list + 16;

    prep_kernel<<<K / 4, 256, 0, stream>>>(coords, c2, chi, counter);
    {
        dim3 g(K / 64, D / 64);
        transpose_kernel<<<g, 256, 0, stream>>>(coords, coordsT);
    }
    // 1 wave/block, 64 rows, full K: 2048 blocks, no barriers
    centroid_mfma_kernel<<<N / 64, 64, 0, stream>>>(latent, chi, c2, out,
                                                    counter, list);
    centroid_exact_kernel<<<2048, 256, 0, stream>>>(latent, coordsT, c2,
                                                    cnt_list, out);
}